// Round 2
// baseline (335.985 us; speedup 1.0000x reference)
//
#include <hip/hip_runtime.h>

#define NB 2
#define NG 1024
#define HEIGHT 128
#define WIDTH 128
#define HW (HEIGHT * WIDTH)
#define NSEG 8
#define SEGLEN (NG / NSEG)           // 128
#define ITEM_STRIDE (8 + SEGLEN * 20 + 8)  // header + items + trailing run = 2576 floats
#define E10 4.5399931e-05f           // exp(-10)

// ws layout (floats)
#define REC_U 0                      // unsorted records: 2048*16
#define REC_S 32768                  // sorted records:   2048*16
#define Z_U   65536                  // unsorted z:       2048
#define ITEMS 67584                  // 16 streams * ITEM_STRIDE = 41216
#define RGBOF 108800                 // rendered rgb:     6*HW = 98304
#define P_ENT 207104                 // 8 entropy partials
#define P_L1D 207112                 // 512 depth-l1 partials
#define P_SSS 207624                 // 384 ssim partials
#define P_SSL 208008                 // 384 rgb-l1 partials
// record: [0]px [1]py [2]hx [3]hy [4]i00 [5]i01 [6]i11 [7]op [8]c0 [9]c1 [10]c2 [11]z [12]e10op [13..15]pad

__device__ inline float blk_reduce(float v, float* sh) {
    for (int off = 32; off > 0; off >>= 1) v += __shfl_down(v, off, 64);
    int lane = threadIdx.x & 63;
    int w = threadIdx.x >> 6;
    __syncthreads();
    if (lane == 0) sh[w] = v;
    __syncthreads();
    float s = 0.f;
    if (threadIdx.x == 0) {
        int nw = (blockDim.x + 63) >> 6;
        for (int i = 0; i < nw; i++) s += sh[i];
    }
    return s;  // valid on thread 0 only
}

// ---------------- per-gaussian preprocess (8 blocks x 256) ----------------
__global__ __launch_bounds__(256) void k_pre(const float* __restrict__ g,
                                             const float* __restrict__ intr,
                                             float* __restrict__ ws) {
    __shared__ float sh[8];
    int idx = blockIdx.x * 256 + threadIdx.x;  // 0..2047
    int b = idx >> 10;
    const float* row = g + (size_t)idx * 38;
    float mx = row[0], my = row[1], mz = row[2];
    float sx = row[3], sy = row[4], sz = row[5];
    float qw = row[6], qx = row[7], qy = row[8], qz = row[9];
    float op = row[10];
    float sh0 = row[11], sh1 = row[12], sh2 = row[13];
    float fx = intr[b * 9 + 0], fy = intr[b * 9 + 4];
    float cx = intr[b * 9 + 2], cy = intr[b * 9 + 5];

    float z = fmaxf(mz, 1e-4f);
    float px = fx * mx / z + cx;
    float py = fy * my / z + cy;

    float r00 = 1.f - 2.f * (qy * qy + qz * qz), r01 = 2.f * (qx * qy - qw * qz), r02 = 2.f * (qx * qz + qw * qy);
    float r10 = 2.f * (qx * qy + qw * qz), r11 = 1.f - 2.f * (qx * qx + qz * qz), r12 = 2.f * (qy * qz - qw * qx);
    float r20 = 2.f * (qx * qz - qw * qy), r21 = 2.f * (qy * qz + qw * qx), r22 = 1.f - 2.f * (qx * qx + qy * qy);
    float a00 = r00 * sx, a01 = r01 * sy, a02 = r02 * sz;
    float a10 = r10 * sx, a11 = r11 * sy, a12 = r12 * sz;
    float a20 = r20 * sx, a21 = r21 * sy, a22 = r22 * sz;
    float m00 = a00 * a00 + a01 * a01 + a02 * a02;
    float m01 = a00 * a10 + a01 * a11 + a02 * a12;
    float m02 = a00 * a20 + a01 * a21 + a02 * a22;
    float m11 = a10 * a10 + a11 * a11 + a12 * a12;
    float m12 = a10 * a20 + a11 * a21 + a12 * a22;
    float m22 = a20 * a20 + a21 * a21 + a22 * a22;

    float zc = fmaxf(mz, 1e-6f);
    float aJ = fx / zc, bJ = -fx * mx / (zc * zc);
    float cJ = fy / zc, dJ = -fy * my / (zc * zc);
    float c00 = aJ * aJ * m00 + 2.f * aJ * bJ * m02 + bJ * bJ * m22 + 0.3f;
    float c01 = cJ * (aJ * m01 + bJ * m12) + dJ * (aJ * m02 + bJ * m22);
    float c11 = cJ * cJ * m11 + 2.f * cJ * dJ * m12 + dJ * dJ * m22 + 0.3f;
    float det = fmaxf(c00 * c11 - c01 * c01, 1e-8f);  // >= 0.09 in practice (0.3I)
    float i00 = c11 / det;
    float i11 = c00 / det;
    float i01 = -c01 / det;

    const float C0c = 0.28209479177387814f;
    float col0 = fminf(fmaxf(sh0 * C0c + 0.5f, 0.f), 1.f);
    float col1 = fminf(fmaxf(sh1 * C0c + 0.5f, 0.f), 1.f);
    float col2 = fminf(fmaxf(sh2 * C0c + 0.5f, 0.f), 1.f);

    float hx = sqrtf(20.f * c00);  // power>-10 ellipse bbox half-extents
    float hy = sqrtf(20.f * c11);

    float* rec = ws + REC_U + (size_t)idx * 16;
    rec[0] = px; rec[1] = py; rec[2] = hx; rec[3] = hy;
    rec[4] = i00; rec[5] = i01; rec[6] = i11; rec[7] = op;
    rec[8] = col0; rec[9] = col1; rec[10] = col2; rec[11] = z;
    rec[12] = E10 * op; rec[13] = 0.f; rec[14] = 0.f; rec[15] = 0.f;
    ws[Z_U + idx] = z;

    float o = fminf(fmaxf(op, 1e-6f), 1.f - 1e-6f);
    float ent = -(o * logf(o) + (1.f - o) * logf(1.f - o));
    float s = blk_reduce(ent, sh);
    if (threadIdx.x == 0) ws[P_ENT + blockIdx.x] = s;
}

// ---------------- rank sort + record scatter (32 blocks x 64) ----------------
__global__ __launch_bounds__(64) void k_rank(float* __restrict__ ws) {
    int gi = blockIdx.x * 64 + threadIdx.x;  // 0..2047
    int b = gi >> 10;
    int i = gi & 1023;
    const float* zb = ws + Z_U + (b << 10);  // wave-uniform base -> s_load
    float zi = zb[i];
    int rank = 0;
    for (int j = 0; j < NG; j += 4) {
        float4 zq = *(const float4*)(zb + j);  // uniform address -> s_load_dwordx4
        rank += (zq.x < zi) || (zq.x == zi && (j + 0) < i);
        rank += (zq.y < zi) || (zq.y == zi && (j + 1) < i);
        rank += (zq.z < zi) || (zq.z == zi && (j + 2) < i);
        rank += (zq.w < zi) || (zq.w == zi && (j + 3) < i);
    }
    const float4* src = (const float4*)(ws + REC_U + (size_t)gi * 16);
    float4 r0 = src[0], r1 = src[1], r2 = src[2], r3 = src[3];
    float4* dst = (float4*)(ws + REC_S + (size_t)((b << 10) + rank) * 16);
    dst[0] = r0; dst[1] = r1; dst[2] = r2; dst[3] = r3;
}

// ---------------- build compacted item streams (16 blocks x 64, lane0) ----------------
__global__ __launch_bounds__(64) void k_items(float* __restrict__ ws) {
    if (threadIdx.x != 0) return;
    int s = blockIdx.x;  // 0..15 = (batch, seg)
    int b = s >> 3, seg = s & 7;
    const float* rec = ws + REC_S + (size_t)((b << 10) + seg * SEGLEN) * 16;
    float* out = ws + ITEMS + (size_t)s * ITEM_STRIDE;
    float rT = 1.f, rr = 0.f, rg = 0.f, rb = 0.f, rd = 0.f;
    int n = 0;
    float* itp = out + 8;
    for (int k = 0; k < SEGLEN; k++) {
        const float* r = rec + k * 16;
        float px = r[0], py = r[1], hx = r[2], hy = r[3];
        bool act = (px + hx >= 0.f) && (px - hx <= 127.f) && (py + hy >= 0.f) && (py - hy <= 127.f);
        if (act) {
            itp[0] = rT; itp[1] = rr; itp[2] = rg; itp[3] = rb; itp[4] = rd;
#pragma unroll
            for (int f = 0; f < 12; f++) itp[5 + f] = r[f];
            itp += 20; n++;
            rT = 1.f; rr = 0.f; rg = 0.f; rb = 0.f; rd = 0.f;
        } else {
            float a = r[12];  // exp(-10)*op, exact clamped alpha
            float ta = rT * a;
            rr += ta * r[8]; rg += ta * r[9]; rb += ta * r[10]; rd += ta * r[11];
            rT = rT - ta;
        }
    }
    itp[0] = rT; itp[1] = rr; itp[2] = rg; itp[3] = rb; itp[4] = rd;
    ((int*)out)[0] = n;
}

// ---------------- render: one 8x8 tile per block, 8 z-segment waves ----------------
__global__ __launch_bounds__(512) void k_render(const float* __restrict__ tgt_d,
                                                float* __restrict__ ws) {
    __shared__ float comb[5][512];
    int tid = threadIdx.x;
    int lane = tid & 63;
    int seg = tid >> 6;
    int blk = blockIdx.x;  // 512 tiles
    int b = blk >> 8;
    int t = blk & 255;
    int x0 = (t & 15) * 8, y0 = (t >> 4) * 8;
    int x = x0 + (lane & 7), y = y0 + (lane >> 3);

    const float* base = ws + ITEMS + (size_t)(b * NSEG + seg) * ITEM_STRIDE;
    int n = ((const int*)base)[0];
    const float* it = base + 8;

    float xf = (float)x, yf = (float)y;
    float x0f = (float)x0, x1f = (float)(x0 + 7);
    float y0f = (float)y0, y1f = (float)(y0 + 7);
    float T = 1.f, cr = 0.f, cg = 0.f, cb = 0.f, cd = 0.f;
    for (int i = 0; i < n; i++, it += 20) {
        // preceding inactive-run composite (scalar data)
        cr += T * it[1]; cg += T * it[2]; cb += T * it[3]; cd += T * it[4];
        T *= it[0];
        // the active gaussian
        float px = it[5], py = it[6], hx = it[7], hy = it[8];
        float op = it[12];
        float c0 = it[13], c1 = it[14], c2 = it[15], z = it[16];
        float a;
        if (px + hx >= x0f && px - hx <= x1f && py + hy >= y0f && py - hy <= y1f) {
            float dx = xf - px, dy = yf - py;
            float q = it[9] * dx * dx + 2.f * it[10] * dx * dy + it[11] * dy * dy;
            float pw = fminf(fmaxf(-0.5f * q, -10.f), 0.f);
            a = fminf(__expf(pw) * op, 0.99f);
        } else {
            a = E10 * op;  // clamped outside its ellipse: pixel-independent
        }
        float w = T * a;
        cr += w * c0; cg += w * c1; cb += w * c2; cd += w * z;
        T -= w;  // T *= (1-a)
    }
    // trailing run
    cr += T * it[1]; cg += T * it[2]; cb += T * it[3]; cd += T * it[4];
    T *= it[0];

    comb[0][tid] = T;
    comb[1][tid] = cr;
    comb[2][tid] = cg;
    comb[3][tid] = cb;
    comb[4][tid] = cd;
    __syncthreads();

    if (tid < 64) {
        float T0 = comb[0][tid], r0 = comb[1][tid], g0 = comb[2][tid];
        float b0 = comb[3][tid], d0 = comb[4][tid];
#pragma unroll
        for (int sgi = 1; sgi < NSEG; sgi++) {
            int j = sgi * 64 + tid;
            r0 += T0 * comb[1][j];
            g0 += T0 * comb[2][j];
            b0 += T0 * comb[3][j];
            d0 += T0 * comb[4][j];
            T0 *= comb[0][j];
        }
        r0 = fminf(fmaxf(r0, 0.f), 1.f);
        g0 = fminf(fmaxf(g0, 0.f), 1.f);
        b0 = fminf(fmaxf(b0, 0.f), 1.f);
        float* rgb = ws + RGBOF;
        rgb[((b * 3 + 0) * HEIGHT + y) * WIDTH + x] = r0;
        rgb[((b * 3 + 1) * HEIGHT + y) * WIDTH + x] = g0;
        rgb[((b * 3 + 2) * HEIGHT + y) * WIDTH + x] = b0;
        float l1d = fabsf(d0 - tgt_d[(b * HEIGHT + y) * WIDTH + x]);
        for (int off = 32; off > 0; off >>= 1) l1d += __shfl_down(l1d, off, 64);
        if (tid == 0) ws[P_L1D + blk] = l1d;
    }
}

// ---------------- SSIM + rgb L1 (384 blocks x 256) ----------------
__global__ __launch_bounds__(256) void k_ssim(const float* __restrict__ tgt_rgb,
                                              float* __restrict__ ws) {
    __shared__ float sh[8];
    int idx = blockIdx.x * 256 + threadIdx.x;  // < 98304
    const float* img1 = ws + RGBOF;
    int bc = idx >> 14;
    int pix = idx & (HW - 1);
    int y = pix >> 7, x = pix & 127;

    float gg[7];
    float gs = 0.f;
#pragma unroll
    for (int i = 0; i < 7; i++) {
        float c = (float)(i - 3);
        gg[i] = __expf(-c * c / 4.5f);
        gs += gg[i];
    }
#pragma unroll
    for (int i = 0; i < 7; i++) gg[i] /= gs;

    float mu1 = 0.f, mu2 = 0.f, s11 = 0.f, s22 = 0.f, s12 = 0.f;
    int plane = bc * HW;
#pragma unroll
    for (int dy = -3; dy <= 3; dy++) {
        int yy = y + dy;
#pragma unroll
        for (int dx = -3; dx <= 3; dx++) {
            int xx = x + dx;
            float w = gg[dy + 3] * gg[dx + 3];
            float i1 = 0.f, i2 = 0.f;
            if (yy >= 0 && yy < HEIGHT && xx >= 0 && xx < WIDTH) {
                int o = plane + yy * WIDTH + xx;
                i1 = img1[o];
                i2 = tgt_rgb[o];
            }
            mu1 += w * i1;
            mu2 += w * i2;
            s11 += w * i1 * i1;
            s22 += w * i2 * i2;
            s12 += w * i1 * i2;
        }
    }
    float v1 = s11 - mu1 * mu1;
    float v2 = s22 - mu2 * mu2;
    float cv = s12 - mu1 * mu2;
    const float C1 = 1e-4f, C2 = 9e-4f;
    float ssim = ((2.f * mu1 * mu2 + C1) * (2.f * cv + C2)) /
                 ((mu1 * mu1 + mu2 * mu2 + C1) * (v1 + v2 + C2));
    float l1 = fabsf(img1[idx] - tgt_rgb[idx]);

    float s_ssim = blk_reduce(ssim, sh);
    float s_l1 = blk_reduce(l1, sh);
    if (threadIdx.x == 0) {
        ws[P_SSS + blockIdx.x] = s_ssim;
        ws[P_SSL + blockIdx.x] = s_l1;
    }
}

// ---------------- final reduce (1 block x 256) ----------------
__global__ __launch_bounds__(256) void k_final(const float* __restrict__ ws_c,
                                               float* __restrict__ out) {
    __shared__ float sh[8];
    float e = 0.f, d = 0.f, ss = 0.f, sl = 0.f;
    for (int i = threadIdx.x; i < 512; i += 256) d += ws_c[P_L1D + i];
    for (int i = threadIdx.x; i < 384; i += 256) { ss += ws_c[P_SSS + i]; sl += ws_c[P_SSL + i]; }
    if (threadIdx.x < 8) e = ws_c[P_ENT + threadIdx.x];
    float rd_ = blk_reduce(d, sh);
    float rss = blk_reduce(ss, sh);
    float rsl = blk_reduce(sl, sh);
    float re = blk_reduce(e, sh);
    if (threadIdx.x == 0) {
        float l1r = rsl / (float)(NB * 3 * HW);
        float ssim = rss / (float)(NB * 3 * HW);
        float l1d = rd_ / (float)(NB * HW);
        float opa = re / (float)(NB * NG);
        out[0] = 0.8f * l1r + 0.2f * (1.f - ssim) + 0.5f * l1d + 0.01f * opa;
    }
}

extern "C" void kernel_launch(void* const* d_in, const int* in_sizes, int n_in,
                              void* d_out, int out_size, void* d_ws, size_t ws_size,
                              hipStream_t stream) {
    const float* g = (const float*)d_in[0];
    const float* intr = (const float*)d_in[1];
    const float* trgb = (const float*)d_in[2];
    const float* tdep = (const float*)d_in[3];
    float* ws = (float*)d_ws;
    float* out = (float*)d_out;

    hipLaunchKernelGGL(k_pre, dim3(8), dim3(256), 0, stream, g, intr, ws);
    hipLaunchKernelGGL(k_rank, dim3(32), dim3(64), 0, stream, ws);
    hipLaunchKernelGGL(k_items, dim3(16), dim3(64), 0, stream, ws);
    hipLaunchKernelGGL(k_render, dim3(NB * 256), dim3(512), 0, stream, tdep, ws);
    hipLaunchKernelGGL(k_ssim, dim3((NB * 3 * HW) / 256), dim3(256), 0, stream, trgb, ws);
    hipLaunchKernelGGL(k_final, dim3(1), dim3(256), 0, stream, ws, out);
}

// Round 3
// 152.815 us; speedup vs baseline: 2.1986x; 2.1986x over previous
//
#include <hip/hip_runtime.h>

#define NB 2
#define NG 1024
#define HEIGHT 128
#define WIDTH 128
#define HW (HEIGHT * WIDTH)
#define NSEG 8
#define SEGLEN (NG / NSEG)           // 128
#define ITEM_STRIDE (8 + SEGLEN * 20 + 8)  // header + items + trailing run = 2576 floats
#define E10 4.5399931e-05f           // exp(-10)

// ws layout (floats)
#define REC_U 0                      // unsorted records: 2048*16
#define REC_S 32768                  // sorted records:   2048*16
#define Z_U   65536                  // unsorted z:       2048
#define ITEMS 67584                  // 16 streams * ITEM_STRIDE = 41216
#define RGBOF 108800                 // rendered rgb:     6*HW = 98304
#define P_ENT 207104                 // 8 entropy partials
#define P_L1D 207112                 // 512 depth-l1 partials
#define P_SSS 207624                 // 384 ssim partials
#define P_SSL 208008                 // 384 rgb-l1 partials
// record: [0]px [1]py [2]hx [3]hy [4]i00 [5]i01 [6]i11 [7]op [8]c0 [9]c1 [10]c2 [11]z [12]e10op [13..15]pad

__device__ inline float blk_reduce(float v, float* sh) {
    for (int off = 32; off > 0; off >>= 1) v += __shfl_down(v, off, 64);
    int lane = threadIdx.x & 63;
    int w = threadIdx.x >> 6;
    __syncthreads();
    if (lane == 0) sh[w] = v;
    __syncthreads();
    float s = 0.f;
    if (threadIdx.x == 0) {
        int nw = (blockDim.x + 63) >> 6;
        for (int i = 0; i < nw; i++) s += sh[i];
    }
    return s;  // valid on thread 0 only
}

// ---------------- per-gaussian preprocess (8 blocks x 256) ----------------
__global__ __launch_bounds__(256) void k_pre(const float* __restrict__ g,
                                             const float* __restrict__ intr,
                                             float* __restrict__ ws) {
    __shared__ float sh[8];
    int idx = blockIdx.x * 256 + threadIdx.x;  // 0..2047
    int b = idx >> 10;
    const float* row = g + (size_t)idx * 38;
    float mx = row[0], my = row[1], mz = row[2];
    float sx = row[3], sy = row[4], sz = row[5];
    float qw = row[6], qx = row[7], qy = row[8], qz = row[9];
    float op = row[10];
    float sh0 = row[11], sh1 = row[12], sh2 = row[13];
    float fx = intr[b * 9 + 0], fy = intr[b * 9 + 4];
    float cx = intr[b * 9 + 2], cy = intr[b * 9 + 5];

    float z = fmaxf(mz, 1e-4f);
    float px = fx * mx / z + cx;
    float py = fy * my / z + cy;

    float r00 = 1.f - 2.f * (qy * qy + qz * qz), r01 = 2.f * (qx * qy - qw * qz), r02 = 2.f * (qx * qz + qw * qy);
    float r10 = 2.f * (qx * qy + qw * qz), r11 = 1.f - 2.f * (qx * qx + qz * qz), r12 = 2.f * (qy * qz - qw * qx);
    float r20 = 2.f * (qx * qz - qw * qy), r21 = 2.f * (qy * qz + qw * qx), r22 = 1.f - 2.f * (qx * qx + qy * qy);
    float a00 = r00 * sx, a01 = r01 * sy, a02 = r02 * sz;
    float a10 = r10 * sx, a11 = r11 * sy, a12 = r12 * sz;
    float a20 = r20 * sx, a21 = r21 * sy, a22 = r22 * sz;
    float m00 = a00 * a00 + a01 * a01 + a02 * a02;
    float m01 = a00 * a10 + a01 * a11 + a02 * a12;
    float m02 = a00 * a20 + a01 * a21 + a02 * a22;
    float m11 = a10 * a10 + a11 * a11 + a12 * a12;
    float m12 = a10 * a20 + a11 * a21 + a12 * a22;
    float m22 = a20 * a20 + a21 * a21 + a22 * a22;

    float zc = fmaxf(mz, 1e-6f);
    float aJ = fx / zc, bJ = -fx * mx / (zc * zc);
    float cJ = fy / zc, dJ = -fy * my / (zc * zc);
    float c00 = aJ * aJ * m00 + 2.f * aJ * bJ * m02 + bJ * bJ * m22 + 0.3f;
    float c01 = cJ * (aJ * m01 + bJ * m12) + dJ * (aJ * m02 + bJ * m22);
    float c11 = cJ * cJ * m11 + 2.f * cJ * dJ * m12 + dJ * dJ * m22 + 0.3f;
    float det = fmaxf(c00 * c11 - c01 * c01, 1e-8f);  // >= 0.09 in practice (0.3I)
    float i00 = c11 / det;
    float i11 = c00 / det;
    float i01 = -c01 / det;

    const float C0c = 0.28209479177387814f;
    float col0 = fminf(fmaxf(sh0 * C0c + 0.5f, 0.f), 1.f);
    float col1 = fminf(fmaxf(sh1 * C0c + 0.5f, 0.f), 1.f);
    float col2 = fminf(fmaxf(sh2 * C0c + 0.5f, 0.f), 1.f);

    float hx = sqrtf(20.f * c00);  // power>-10 ellipse bbox half-extents
    float hy = sqrtf(20.f * c11);

    float* rec = ws + REC_U + (size_t)idx * 16;
    rec[0] = px; rec[1] = py; rec[2] = hx; rec[3] = hy;
    rec[4] = i00; rec[5] = i01; rec[6] = i11; rec[7] = op;
    rec[8] = col0; rec[9] = col1; rec[10] = col2; rec[11] = z;
    rec[12] = E10 * op; rec[13] = 0.f; rec[14] = 0.f; rec[15] = 0.f;
    ws[Z_U + idx] = z;

    float o = fminf(fmaxf(op, 1e-6f), 1.f - 1e-6f);
    float ent = -(o * logf(o) + (1.f - o) * logf(1.f - o));
    float s = blk_reduce(ent, sh);
    if (threadIdx.x == 0) ws[P_ENT + blockIdx.x] = s;
}

// ---------------- rank sort + record scatter (32 blocks x 64) ----------------
__global__ __launch_bounds__(64) void k_rank(float* __restrict__ ws) {
    int gi = blockIdx.x * 64 + threadIdx.x;  // 0..2047
    int b = gi >> 10;
    int i = gi & 1023;
    const float* zb = ws + Z_U + (b << 10);  // wave-uniform base -> s_load
    float zi = zb[i];
    int rank = 0;
    for (int j = 0; j < NG; j += 4) {
        float4 zq = *(const float4*)(zb + j);  // uniform address -> s_load_dwordx4
        rank += (zq.x < zi) || (zq.x == zi && (j + 0) < i);
        rank += (zq.y < zi) || (zq.y == zi && (j + 1) < i);
        rank += (zq.z < zi) || (zq.z == zi && (j + 2) < i);
        rank += (zq.w < zi) || (zq.w == zi && (j + 3) < i);
    }
    const float4* src = (const float4*)(ws + REC_U + (size_t)gi * 16);
    float4 r0 = src[0], r1 = src[1], r2 = src[2], r3 = src[3];
    float4* dst = (float4*)(ws + REC_S + (size_t)((b << 10) + rank) * 16);
    dst[0] = r0; dst[1] = r1; dst[2] = r2; dst[3] = r3;
}

// ---------------- build compacted item streams: segmented scan ----------------
// One block (128 threads) per stream. Affine map per gaussian:
// inactive j: (T,c) -> (T*(1-a_j), c + T*a_j*col_j)   with a_j = exp(-10)*op_j
// active   j: identity + segment flag (scan resets after it).
// Run-before-active-k = scan value at k-1; trailing run = scan value at 127.
__global__ __launch_bounds__(128) void k_items(float* __restrict__ ws) {
    __shared__ float sT[128], sr[128], sg[128], sb[128], sd[128];
    __shared__ int sf[128], sx[128];
    int s = blockIdx.x;  // 0..15 = (batch, seg)
    int b = s >> 3, seg = s & 7;
    int k = threadIdx.x;
    const float* r = ws + REC_S + (size_t)((b << 10) + seg * SEGLEN + k) * 16;
    float4 q0 = ((const float4*)r)[0];  // px py hx hy
    float4 q1 = ((const float4*)r)[1];  // i00 i01 i11 op
    float4 q2 = ((const float4*)r)[2];  // c0 c1 c2 z
    float a10 = r[12];                  // exp(-10)*op
    bool act = (q0.x + q0.z >= 0.f) && (q0.x - q0.z <= 127.f) &&
               (q0.y + q0.w >= 0.f) && (q0.y - q0.w <= 127.f);
    if (act) {
        sT[k] = 1.f; sr[k] = 0.f; sg[k] = 0.f; sb[k] = 0.f; sd[k] = 0.f;
        sf[k] = 1; sx[k] = 1;
    } else {
        sT[k] = 1.f - a10;
        sr[k] = a10 * q2.x; sg[k] = a10 * q2.y; sb[k] = a10 * q2.z; sd[k] = a10 * q2.w;
        sf[k] = 0; sx[k] = 0;
    }
    __syncthreads();
#pragma unroll
    for (int off = 1; off < 128; off <<= 1) {
        float pT = 1.f, pr = 0.f, pg = 0.f, pb = 0.f, pd = 0.f;
        int pf = 0, px_ = 0;
        if (k >= off) {
            pT = sT[k - off]; pr = sr[k - off]; pg = sg[k - off];
            pb = sb[k - off]; pd = sd[k - off]; pf = sf[k - off]; px_ = sx[k - off];
        }
        __syncthreads();
        if (k >= off) {
            sx[k] += px_;
            if (!sf[k]) {  // absorb left partial unless a segment starts inside ours
                sr[k] = pr + pT * sr[k];
                sg[k] = pg + pT * sg[k];
                sb[k] = pb + pT * sb[k];
                sd[k] = pd + pT * sd[k];
                sT[k] = pT * sT[k];
                sf[k] = pf;
            }
        }
        __syncthreads();
    }
    float* out = ws + ITEMS + (size_t)s * ITEM_STRIDE;
    int n = sx[127];
    if (act) {
        float* itp = out + 8 + (size_t)(sx[k] - 1) * 20;
        if (k == 0) {
            itp[0] = 1.f; itp[1] = 0.f; itp[2] = 0.f; itp[3] = 0.f; itp[4] = 0.f;
        } else {
            itp[0] = sT[k - 1]; itp[1] = sr[k - 1]; itp[2] = sg[k - 1];
            itp[3] = sb[k - 1]; itp[4] = sd[k - 1];
        }
        itp[5] = q0.x; itp[6] = q0.y; itp[7] = q0.z; itp[8] = q0.w;
        itp[9] = q1.x; itp[10] = q1.y; itp[11] = q1.z; itp[12] = q1.w;
        itp[13] = q2.x; itp[14] = q2.y; itp[15] = q2.z; itp[16] = q2.w;
    }
    if (k == 127) {  // trailing run (identity if 127 is active)
        float* itp = out + 8 + (size_t)n * 20;
        itp[0] = sT[127]; itp[1] = sr[127]; itp[2] = sg[127];
        itp[3] = sb[127]; itp[4] = sd[127];
    }
    if (k == 0) ((int*)out)[0] = n;
}

// ---------------- render: one 8x8 tile per block, 8 z-segment waves ----------------
__global__ __launch_bounds__(512) void k_render(const float* __restrict__ tgt_d,
                                                float* __restrict__ ws) {
    __shared__ float comb[5][512];
    int tid = threadIdx.x;
    int lane = tid & 63;
    int seg = tid >> 6;
    int blk = blockIdx.x;  // 512 tiles
    int b = blk >> 8;
    int t = blk & 255;
    int x0 = (t & 15) * 8, y0 = (t >> 4) * 8;
    int x = x0 + (lane & 7), y = y0 + (lane >> 3);

    const float* base = ws + ITEMS + (size_t)(b * NSEG + seg) * ITEM_STRIDE;
    int n = ((const int*)base)[0];
    const float* it = base + 8;

    float xf = (float)x, yf = (float)y;
    float x0f = (float)x0, x1f = (float)(x0 + 7);
    float y0f = (float)y0, y1f = (float)(y0 + 7);
    float T = 1.f, cr = 0.f, cg = 0.f, cb = 0.f, cd = 0.f;
    for (int i = 0; i < n; i++, it += 20) {
        // preceding inactive-run composite (scalar data)
        cr += T * it[1]; cg += T * it[2]; cb += T * it[3]; cd += T * it[4];
        T *= it[0];
        // the active gaussian
        float px = it[5], py = it[6], hx = it[7], hy = it[8];
        float op = it[12];
        float c0 = it[13], c1 = it[14], c2 = it[15], z = it[16];
        float a;
        if (px + hx >= x0f && px - hx <= x1f && py + hy >= y0f && py - hy <= y1f) {
            float dx = xf - px, dy = yf - py;
            float q = it[9] * dx * dx + 2.f * it[10] * dx * dy + it[11] * dy * dy;
            float pw = fminf(fmaxf(-0.5f * q, -10.f), 0.f);
            a = fminf(__expf(pw) * op, 0.99f);
        } else {
            a = E10 * op;  // clamped outside its ellipse: pixel-independent
        }
        float w = T * a;
        cr += w * c0; cg += w * c1; cb += w * c2; cd += w * z;
        T -= w;  // T *= (1-a)
    }
    // trailing run
    cr += T * it[1]; cg += T * it[2]; cb += T * it[3]; cd += T * it[4];
    T *= it[0];

    comb[0][tid] = T;
    comb[1][tid] = cr;
    comb[2][tid] = cg;
    comb[3][tid] = cb;
    comb[4][tid] = cd;
    __syncthreads();

    if (tid < 64) {
        float T0 = comb[0][tid], r0 = comb[1][tid], g0 = comb[2][tid];
        float b0 = comb[3][tid], d0 = comb[4][tid];
#pragma unroll
        for (int sgi = 1; sgi < NSEG; sgi++) {
            int j = sgi * 64 + tid;
            r0 += T0 * comb[1][j];
            g0 += T0 * comb[2][j];
            b0 += T0 * comb[3][j];
            d0 += T0 * comb[4][j];
            T0 *= comb[0][j];
        }
        r0 = fminf(fmaxf(r0, 0.f), 1.f);
        g0 = fminf(fmaxf(g0, 0.f), 1.f);
        b0 = fminf(fmaxf(b0, 0.f), 1.f);
        float* rgb = ws + RGBOF;
        rgb[((b * 3 + 0) * HEIGHT + y) * WIDTH + x] = r0;
        rgb[((b * 3 + 1) * HEIGHT + y) * WIDTH + x] = g0;
        rgb[((b * 3 + 2) * HEIGHT + y) * WIDTH + x] = b0;
        float l1d = fabsf(d0 - tgt_d[(b * HEIGHT + y) * WIDTH + x]);
        for (int off = 32; off > 0; off >>= 1) l1d += __shfl_down(l1d, off, 64);
        if (tid == 0) ws[P_L1D + blk] = l1d;
    }
}

// ---------------- SSIM + rgb L1 (384 blocks x 256) ----------------
__global__ __launch_bounds__(256) void k_ssim(const float* __restrict__ tgt_rgb,
                                              float* __restrict__ ws) {
    __shared__ float sh[8];
    int idx = blockIdx.x * 256 + threadIdx.x;  // < 98304
    const float* img1 = ws + RGBOF;
    int bc = idx >> 14;
    int pix = idx & (HW - 1);
    int y = pix >> 7, x = pix & 127;

    float gg[7];
    float gs = 0.f;
#pragma unroll
    for (int i = 0; i < 7; i++) {
        float c = (float)(i - 3);
        gg[i] = __expf(-c * c / 4.5f);
        gs += gg[i];
    }
#pragma unroll
    for (int i = 0; i < 7; i++) gg[i] /= gs;

    float mu1 = 0.f, mu2 = 0.f, s11 = 0.f, s22 = 0.f, s12 = 0.f;
    int plane = bc * HW;
#pragma unroll
    for (int dy = -3; dy <= 3; dy++) {
        int yy = y + dy;
#pragma unroll
        for (int dx = -3; dx <= 3; dx++) {
            int xx = x + dx;
            float w = gg[dy + 3] * gg[dx + 3];
            float i1 = 0.f, i2 = 0.f;
            if (yy >= 0 && yy < HEIGHT && xx >= 0 && xx < WIDTH) {
                int o = plane + yy * WIDTH + xx;
                i1 = img1[o];
                i2 = tgt_rgb[o];
            }
            mu1 += w * i1;
            mu2 += w * i2;
            s11 += w * i1 * i1;
            s22 += w * i2 * i2;
            s12 += w * i1 * i2;
        }
    }
    float v1 = s11 - mu1 * mu1;
    float v2 = s22 - mu2 * mu2;
    float cv = s12 - mu1 * mu2;
    const float C1 = 1e-4f, C2 = 9e-4f;
    float ssim = ((2.f * mu1 * mu2 + C1) * (2.f * cv + C2)) /
                 ((mu1 * mu1 + mu2 * mu2 + C1) * (v1 + v2 + C2));
    float l1 = fabsf(img1[idx] - tgt_rgb[idx]);

    float s_ssim = blk_reduce(ssim, sh);
    float s_l1 = blk_reduce(l1, sh);
    if (threadIdx.x == 0) {
        ws[P_SSS + blockIdx.x] = s_ssim;
        ws[P_SSL + blockIdx.x] = s_l1;
    }
}

// ---------------- final reduce (1 block x 256) ----------------
__global__ __launch_bounds__(256) void k_final(const float* __restrict__ ws_c,
                                               float* __restrict__ out) {
    __shared__ float sh[8];
    float e = 0.f, d = 0.f, ss = 0.f, sl = 0.f;
    for (int i = threadIdx.x; i < 512; i += 256) d += ws_c[P_L1D + i];
    for (int i = threadIdx.x; i < 384; i += 256) { ss += ws_c[P_SSS + i]; sl += ws_c[P_SSL + i]; }
    if (threadIdx.x < 8) e = ws_c[P_ENT + threadIdx.x];
    float rd_ = blk_reduce(d, sh);
    float rss = blk_reduce(ss, sh);
    float rsl = blk_reduce(sl, sh);
    float re = blk_reduce(e, sh);
    if (threadIdx.x == 0) {
        float l1r = rsl / (float)(NB * 3 * HW);
        float ssim = rss / (float)(NB * 3 * HW);
        float l1d = rd_ / (float)(NB * HW);
        float opa = re / (float)(NB * NG);
        out[0] = 0.8f * l1r + 0.2f * (1.f - ssim) + 0.5f * l1d + 0.01f * opa;
    }
}

extern "C" void kernel_launch(void* const* d_in, const int* in_sizes, int n_in,
                              void* d_out, int out_size, void* d_ws, size_t ws_size,
                              hipStream_t stream) {
    const float* g = (const float*)d_in[0];
    const float* intr = (const float*)d_in[1];
    const float* trgb = (const float*)d_in[2];
    const float* tdep = (const float*)d_in[3];
    float* ws = (float*)d_ws;
    float* out = (float*)d_out;

    hipLaunchKernelGGL(k_pre, dim3(8), dim3(256), 0, stream, g, intr, ws);
    hipLaunchKernelGGL(k_rank, dim3(32), dim3(64), 0, stream, ws);
    hipLaunchKernelGGL(k_items, dim3(16), dim3(128), 0, stream, ws);
    hipLaunchKernelGGL(k_render, dim3(NB * 256), dim3(512), 0, stream, tdep, ws);
    hipLaunchKernelGGL(k_ssim, dim3((NB * 3 * HW) / 256), dim3(256), 0, stream, trgb, ws);
    hipLaunchKernelGGL(k_final, dim3(1), dim3(256), 0, stream, ws, out);
}